// Round 9
// baseline (659.267 us; speedup 1.0000x reference)
//
#include <hip/hip_runtime.h>
#include <hip/hip_bf16.h>
#include <math.h>

// Problem constants (fixed by setup_inputs)
#define BB 16
#define CC 192
#define TS 2048
#define TT 512
#define KK 384   // 2*CC

// d_out float offsets
#define OFF_PATH 0
#define OFF_DUR  (16777216)
#define OFF_LOGW (OFF_DUR + 8192)
#define OFF_MEXP (OFF_LOGW + 8192)
#define OFF_LEXP (OFF_MEXP + 6291456)
#define OFF_TMASK (OFF_LEXP + 6291456)
#define OFF_SMASK (OFF_TMASK + 8192)

#define NEGCF (-1e9f)
#define GSTR (TT*4)          // floats per t-group in ncT = 2048

// ---------------------------------------------------------------------------
// prep: per (b,u): s = exp(-2 logs), Bmat rows {m*s, s}, avec = nc1+nc4,
// plus text_mask / spec_mask outputs.
__global__ __launch_bounds__(512) void vits_prep(
    const float* __restrict__ m_p, const float* __restrict__ logs_p,
    const int* __restrict__ spec_len, const int* __restrict__ text_len,
    float* __restrict__ Bmat, float* __restrict__ avec,
    float* __restrict__ tmask, float* __restrict__ smask)
{
    const int b = blockIdx.x;
    const int u = threadIdx.x;
    const float C0 = -0.91893853320467274178f; // -0.5*log(2*pi)
    float a_acc = 0.f;
    for (int c = 0; c < CC; ++c) {
        float lg = logs_p[((size_t)b*CC + c)*TT + u];
        float mm = m_p[((size_t)b*CC + c)*TT + u];
        float s  = expf(-2.f*lg);
        float ms = mm * s;
        Bmat[((size_t)b*KK + 2*c    )*TT + u] = ms;  // pairs with z      -> neg_cent3
        Bmat[((size_t)b*KK + 2*c + 1)*TT + u] = s;   // pairs with -.5z^2 -> neg_cent2
        a_acc += C0 - lg - 0.5f*mm*ms;               // nc1 + nc4 terms
    }
    avec[b*TT + u] = a_acc;
    tmask[b*TT + u] = (u < text_len[b]) ? 1.f : 0.f;
    for (int t = u; t < TS; t += TT)
        smask[b*TS + t] = (t < spec_len[b]) ? 1.f : 0.f;
}

// ---------------------------------------------------------------------------
// gemm: ncT[b][g][u][k] = avec[b][u] + sum_k X[*][t=4g+k] * Bmat[*][u]
// (time-blocked transposed output so the DP can load 4 timesteps per instr)
__global__ __launch_bounds__(256) void vits_gemm(
    const float* __restrict__ z, const float* __restrict__ Bmat,
    const float* __restrict__ avec, float* __restrict__ ncT)
{
    const int b  = blockIdx.z;
    const int t0 = blockIdx.y * 64;
    const int u0 = blockIdx.x * 64;
    __shared__ float As[16][68];
    __shared__ float Bs[16][68];
    const int tid = threadIdx.x;
    const int tx = tid & 15, ty = tid >> 4;
    float acc[4][4] = {};
    const float* zb = z    + (size_t)b * CC * TS;
    const float* Bb = Bmat + (size_t)b * KK * TT;
    for (int kc = 0; kc < KK/16; ++kc) {
        {
            int c_l = tid >> 5;            // 0..7
            int t_l = (tid & 31) * 2;
            const float* zp = zb + (size_t)(kc*8 + c_l)*TS + t0 + t_l;
            float2 zv = *(const float2*)zp;
            float2 z1 = make_float2(zv.x, zv.y);
            float2 z2 = make_float2(-0.5f*zv.x*zv.x, -0.5f*zv.y*zv.y);
            *(float2*)&As[2*c_l  ][t_l] = z1;
            *(float2*)&As[2*c_l+1][t_l] = z2;
            int k_l = tid >> 4;            // 0..15
            int u_l = (tid & 15) * 4;
            const float* bp = Bb + (size_t)(kc*16 + k_l)*TT + u0 + u_l;
            *(float4*)&Bs[k_l][u_l] = *(const float4*)bp;
        }
        __syncthreads();
        #pragma unroll
        for (int kk = 0; kk < 16; ++kk) {
            float4 av = *(const float4*)&As[kk][ty*4];
            float4 bv = *(const float4*)&Bs[kk][tx*4];
            float aa[4] = {av.x, av.y, av.z, av.w};
            float bb[4] = {bv.x, bv.y, bv.z, bv.w};
            #pragma unroll
            for (int i = 0; i < 4; ++i)
                #pragma unroll
                for (int jj = 0; jj < 4; ++jj)
                    acc[i][jj] += aa[i]*bb[jj];
        }
        __syncthreads();
    }
    float4 a4 = *(const float4*)(avec + b*TT + u0 + tx*4);
    float ab[4] = {a4.x, a4.y, a4.z, a4.w};
    const int g = (t0 >> 2) + ty;                 // t-group (t = 4g+i)
    float* outp = ncT + (((size_t)b*(TS/4) + g)*TT + u0 + tx*4) * 4;
    #pragma unroll
    for (int jj = 0; jj < 4; ++jj) {
        float4 o;
        o.x = acc[0][jj] + ab[jj];
        o.y = acc[1][jj] + ab[jj];
        o.z = acc[2][jj] + ab[jj];
        o.w = acc[3][jj] + ab[jj];
        *(float4*)(outp + jj*4) = o;              // 4 consecutive 16B blocks/thread
    }
}

// ---------------------------------------------------------------------------
// DPP full-wave rotate-by-1: lane n <- lane (n-1)&63 (wave_ror:1 = 0x13C).
__device__ __forceinline__ float dpp_ror1_f32(float v) {
    union { float f; int i; } u, r;
    u.f = v;
    r.i = __builtin_amdgcn_update_dpp(0, u.i, 0x13C, 0xF, 0xF, false);
    return r.f;
}

// ---------------------------------------------------------------------------
// dp: forward Viterbi (f32), 16-wave ghost-zone tiling, transposed nc loads.
// Wave w: lanes 32-63 own auth columns w*32..w*32+31; lanes 0-31 ghost-copy
// the left wave's columns. col = w*32+lane-32; wave_ror1 provides col-1.
// Ghost lane 0 takes junk; corruption moves 1 lane/step and reaches auth
// only after 33 steps > 32-step refresh cadence.
// Loads: ncT[b][t/4][col][4] -> one float4 covers 4 steps; 8 loads per
// 32-step block, double-buffered (bufA/bufB, all static indices), issued a
// full block ahead of the single per-block barrier -> no barrier drain cost.
// dirs bit-packed per auth col along t (32-t windows), bank-swizzled.
#define DIRS(j,w) dirs[((j)<<6) | ((w) ^ ((j) & 31))]

__global__ __launch_bounds__(1024, 1) void vits_dp(
    const float* __restrict__ ncT,
    const int* __restrict__ spec_len, const int* __restrict__ text_len,
    float* __restrict__ dur, float* __restrict__ logw, int* __restrict__ jt)
{
    __shared__ unsigned int dirs[TT*(TS/32)];   // 128 KB (swizzled)
    __shared__ float qrow2[2][TT];              // 4 KB (double-buffered)
    __shared__ int Tr[TT + 1];                  // 2 KB

    const int tid  = threadIdx.x;
    const int lane = tid & 63;
    const int wid  = tid >> 6;
    const int b = blockIdx.x;
    const int SL = spec_len[b], TL = text_len[b];
    const int col = (wid << 5) + lane - 32;      // auth if lane>=32, ghost else
    const bool auth = (lane >= 32);
    const bool w0g  = (wid == 0) && (lane < 32); // pinned-NEG ghost lanes
    const int colL = (col < 0) ? 0 : col;

    float q = (col == 0) ? 0.0f : NEGCF;
    unsigned int bits = 0;

    const float* base = ncT + (size_t)b*(TS/4)*GSTR + (size_t)colL*4;

    float4 bufA[8], bufB[8];
    #pragma unroll
    for (int i = 0; i < 8; ++i) bufA[i] = *(const float4*)(base + (size_t)i*GSTR);

#define PHASE(BUF, OBUF, PAR) do {                                           \
        const int tn4 = (tb + 32) >> 2;                                      \
        _Pragma("unroll")                                                    \
        for (int i = 0; i < 8; ++i) {                                        \
            int gi = tn4 + i; if (gi > TS/4 - 1) gi = TS/4 - 1;              \
            OBUF[i] = *(const float4*)(base + (size_t)gi*GSTR);              \
        }                                                                    \
        _Pragma("unroll")                                                    \
        for (int g4 = 0; g4 < 8; ++g4) {                                     \
            _Pragma("unroll")                                                \
            for (int k = 0; k < 4; ++k) {                                    \
                float f = ((const float*)&BUF[g4])[k];                       \
                float qp = dpp_ror1_f32(q);                                  \
                bool d = (qp >= q);                                          \
                bits = (bits << 1) | (unsigned)d;                            \
                float qn = f + fmaxf(qp, q);                                 \
                q = w0g ? NEGCF : qn;                                        \
            }                                                                \
        }                                                                    \
        if (auth) { DIRS(col, tb >> 5) = bits; qrow2[PAR][col] = q; }        \
        bits = 0;                                                            \
        __syncthreads();                                                     \
        if (!auth && wid) q = qrow2[PAR][col];                               \
    } while (0)

    int tb = 0;
    const int nblk = SL >> 5;
    for (int blk = 0; blk < nblk; ++blk, tb += 32) {
        if ((blk & 1) == 0) PHASE(bufA, bufB, 0);
        else                PHASE(bufB, bufA, 1);
    }
    // tail (SL & 31 steps, <32 so no in-loop dirs write)
    for (int t = tb; t < SL; ++t) {
        float f = base[((size_t)(t >> 2))*GSTR + (t & 3)];
        float qp = dpp_ror1_f32(q);
        bool d = (qp >= q);
        bits = (bits << 1) | (unsigned)d;
        float qn = f + fmaxf(qp, q);
        q = w0g ? NEGCF : qn;
    }
    if (SL & 31) {
        int w = SL >> 5, r = SL & 31;
        if (auth) DIRS(col, w) = bits << (32 - r);
    }
    __syncthreads();

    for (int i = tid; i <= TT; i += 1024) Tr[i] = 0;
    __syncthreads();

    if (tid == 0) {
        Tr[TL] = SL;
        int j = TL - 1, tc = SL - 1;
        // Tr[j] = first frame aligned to text index j (transition time)
        while (j > 0 && tc >= 0) {
            int w = tc >> 5;
            int bcur = 31 - (tc & 31);
            unsigned int W = DIRS(j, w) & (0xFFFFFFFFu << bcur);
            if (W) {
                int bp = __ffs(W) - 1;          // lowest set bit >= bcur
                int tp = (w << 5) + 31 - bp;    // = largest t' <= tc with d=1
                Tr[j] = tp;
                --j;
                tc = tp - 1;
            } else {
                if (w == 0) break;
                tc = (w << 5) - 1;
            }
        }
    }
    __syncthreads();

    for (int u = tid; u < TT; u += 1024) {
        float dv = (u < TL) ? (float)(Tr[u+1] - Tr[u]) : 0.0f;
        dur[b*TT + u] = dv;
        logw[b*TT + u] = (u < TL) ? logf(dv + 1e-6f) : 0.0f;
    }
    // jt: range-fill [Tr[u], Tr[u+1]) -> u
    for (int u = 0; u < TL; ++u) {
        int t1 = Tr[u+1];
        for (int t = Tr[u] + tid; t < t1; t += 1024) jt[b*TS + t] = u;
    }
    for (int t = SL + tid; t < TS; t += 1024) jt[b*TS + t] = -1;
}

// ---------------------------------------------------------------------------
// path: path[b][t][u] = (u == jt[b][t]) ? 1 : 0   (float4-vectorized)
__global__ void vits_path(const int* __restrict__ jt, float4* __restrict__ path)
{
    int idx = blockIdx.x*blockDim.x + threadIdx.x;
    const int total = BB*TS*(TT/4);
    for (; idx < total; idx += gridDim.x*blockDim.x) {
        int u4 = idx & (TT/4 - 1);
        int bt = idx >> 7;
        int j = jt[bt];
        float4 v = make_float4(0.f,0.f,0.f,0.f);
        int r = j - (u4 << 2);
        if (r >= 0 && r < 4) ((float*)&v)[r] = 1.f;
        path[idx] = v;
    }
}

// ---------------------------------------------------------------------------
// m/logs expansion: out[b][c][t] = (jt>=0) ? src[b][c][jt] : 0
__global__ void vits_mlexp(const int* __restrict__ jt,
    const float* __restrict__ m_p, const float* __restrict__ logs_p,
    float4* __restrict__ mexp, float4* __restrict__ lexp)
{
    int idx = blockIdx.x*blockDim.x + threadIdx.x;
    const int total = BB*CC*(TS/4);
    for (; idx < total; idx += gridDim.x*blockDim.x) {
        int t4 = idx & (TS/4 - 1);
        int bc = idx >> 9;
        int b = bc / CC;
        int4 jv = *(const int4*)(jt + b*TS + (t4 << 2));
        const float* mrow = m_p    + (size_t)bc*TT;
        const float* lrow = logs_p + (size_t)bc*TT;
        float4 mv, lv;
        mv.x = (jv.x >= 0) ? mrow[jv.x] : 0.f;  lv.x = (jv.x >= 0) ? lrow[jv.x] : 0.f;
        mv.y = (jv.y >= 0) ? mrow[jv.y] : 0.f;  lv.y = (jv.y >= 0) ? lrow[jv.y] : 0.f;
        mv.z = (jv.z >= 0) ? mrow[jv.z] : 0.f;  lv.z = (jv.z >= 0) ? lrow[jv.z] : 0.f;
        mv.w = (jv.w >= 0) ? mrow[jv.w] : 0.f;  lv.w = (jv.w >= 0) ? lrow[jv.w] : 0.f;
        mexp[idx] = mv;
        lexp[idx] = lv;
    }
}

// ---------------------------------------------------------------------------
extern "C" void kernel_launch(void* const* d_in, const int* in_sizes, int n_in,
                              void* d_out, int out_size, void* d_ws, size_t ws_size,
                              hipStream_t stream) {
    const float* z_p      = (const float*)d_in[0];
    const float* m_p      = (const float*)d_in[1];
    const float* logs_p   = (const float*)d_in[2];
    const int*   spec_len = (const int*)d_in[3];
    const int*   text_len = (const int*)d_in[4];
    float* out = (float*)d_out;

    float* Bmat = (float*)d_ws;                  // [B][384][512] f32 = 12.6 MB
    float* avec = Bmat + (size_t)BB*KK*TT;       // [B][512]
    int*   jt   = (int*)(avec + BB*TT);          // [B][2048]

    float* path  = out + OFF_PATH;   // doubles as ncT staging ([B][TS/4][TT][4])
    float* dur   = out + OFF_DUR;
    float* logw  = out + OFF_LOGW;
    float* mexp  = out + OFF_MEXP;
    float* lexp  = out + OFF_LEXP;
    float* tmask = out + OFF_TMASK;
    float* smask = out + OFF_SMASK;

    vits_prep<<<BB, 512, 0, stream>>>(m_p, logs_p, spec_len, text_len,
                                      Bmat, avec, tmask, smask);
    vits_gemm<<<dim3(TT/64, TS/64, BB), 256, 0, stream>>>(z_p, Bmat, avec, path);
    vits_dp<<<BB, 1024, 0, stream>>>(path, spec_len, text_len, dur, logw, jt);
    vits_path<<<2048, 256, 0, stream>>>(jt, (float4*)path);
    vits_mlexp<<<2048, 256, 0, stream>>>(jt, m_p, logs_p, (float4*)mexp, (float4*)lexp);
}

// Round 10
// 499.694 us; speedup vs baseline: 1.3193x; 1.3193x over previous
//
#include <hip/hip_runtime.h>
#include <hip/hip_bf16.h>
#include <math.h>

// Problem constants (fixed by setup_inputs)
#define BB 16
#define CC 192
#define TS 2048
#define TT 512
#define KK 384   // 2*CC

// d_out float offsets
#define OFF_PATH 0
#define OFF_DUR  (16777216)
#define OFF_LOGW (OFF_DUR + 8192)
#define OFF_MEXP (OFF_LOGW + 8192)
#define OFF_LEXP (OFF_MEXP + 6291456)
#define OFF_TMASK (OFF_LEXP + 6291456)
#define OFF_SMASK (OFF_TMASK + 8192)

#define NEGCF (-1e9f)
#define GSTR (TT*4)          // floats per t-group in ncT = 2048

// ---------------------------------------------------------------------------
// prep: per (b,u): s = exp(-2 logs), Bmat rows {m*s, s}, avec = nc1+nc4,
// plus text_mask / spec_mask outputs.
__global__ __launch_bounds__(512) void vits_prep(
    const float* __restrict__ m_p, const float* __restrict__ logs_p,
    const int* __restrict__ spec_len, const int* __restrict__ text_len,
    float* __restrict__ Bmat, float* __restrict__ avec,
    float* __restrict__ tmask, float* __restrict__ smask)
{
    const int b = blockIdx.x;
    const int u = threadIdx.x;
    const float C0 = -0.91893853320467274178f; // -0.5*log(2*pi)
    float a_acc = 0.f;
    for (int c = 0; c < CC; ++c) {
        float lg = logs_p[((size_t)b*CC + c)*TT + u];
        float mm = m_p[((size_t)b*CC + c)*TT + u];
        float s  = expf(-2.f*lg);
        float ms = mm * s;
        Bmat[((size_t)b*KK + 2*c    )*TT + u] = ms;  // pairs with z      -> neg_cent3
        Bmat[((size_t)b*KK + 2*c + 1)*TT + u] = s;   // pairs with -.5z^2 -> neg_cent2
        a_acc += C0 - lg - 0.5f*mm*ms;               // nc1 + nc4 terms
    }
    avec[b*TT + u] = a_acc;
    tmask[b*TT + u] = (u < text_len[b]) ? 1.f : 0.f;
    for (int t = u; t < TS; t += TT)
        smask[b*TS + t] = (t < spec_len[b]) ? 1.f : 0.f;
}

// ---------------------------------------------------------------------------
// gemm: ncT[b][g][u][k] = avec[b][u] + sum_k X[*][t=4g+k] * Bmat[*][u]
// (time-blocked transposed output so the DP can load 4 timesteps per instr)
__global__ __launch_bounds__(256) void vits_gemm(
    const float* __restrict__ z, const float* __restrict__ Bmat,
    const float* __restrict__ avec, float* __restrict__ ncT)
{
    const int b  = blockIdx.z;
    const int t0 = blockIdx.y * 64;
    const int u0 = blockIdx.x * 64;
    __shared__ float As[16][68];
    __shared__ float Bs[16][68];
    const int tid = threadIdx.x;
    const int tx = tid & 15, ty = tid >> 4;
    float acc[4][4] = {};
    const float* zb = z    + (size_t)b * CC * TS;
    const float* Bb = Bmat + (size_t)b * KK * TT;
    for (int kc = 0; kc < KK/16; ++kc) {
        {
            int c_l = tid >> 5;            // 0..7
            int t_l = (tid & 31) * 2;
            const float* zp = zb + (size_t)(kc*8 + c_l)*TS + t0 + t_l;
            float2 zv = *(const float2*)zp;
            float2 z1 = make_float2(zv.x, zv.y);
            float2 z2 = make_float2(-0.5f*zv.x*zv.x, -0.5f*zv.y*zv.y);
            *(float2*)&As[2*c_l  ][t_l] = z1;
            *(float2*)&As[2*c_l+1][t_l] = z2;
            int k_l = tid >> 4;            // 0..15
            int u_l = (tid & 15) * 4;
            const float* bp = Bb + (size_t)(kc*16 + k_l)*TT + u0 + u_l;
            *(float4*)&Bs[k_l][u_l] = *(const float4*)bp;
        }
        __syncthreads();
        #pragma unroll
        for (int kk = 0; kk < 16; ++kk) {
            float4 av = *(const float4*)&As[kk][ty*4];
            float4 bv = *(const float4*)&Bs[kk][tx*4];
            float aa[4] = {av.x, av.y, av.z, av.w};
            float bb[4] = {bv.x, bv.y, bv.z, bv.w};
            #pragma unroll
            for (int i = 0; i < 4; ++i)
                #pragma unroll
                for (int jj = 0; jj < 4; ++jj)
                    acc[i][jj] += aa[i]*bb[jj];
        }
        __syncthreads();
    }
    float4 a4 = *(const float4*)(avec + b*TT + u0 + tx*4);
    float ab[4] = {a4.x, a4.y, a4.z, a4.w};
    const int g = (t0 >> 2) + ty;                 // t-group (t = 4g+i)
    float* outp = ncT + (((size_t)b*(TS/4) + g)*TT + u0 + tx*4) * 4;
    #pragma unroll
    for (int jj = 0; jj < 4; ++jj) {
        float4 o;
        o.x = acc[0][jj] + ab[jj];
        o.y = acc[1][jj] + ab[jj];
        o.z = acc[2][jj] + ab[jj];
        o.w = acc[3][jj] + ab[jj];
        *(float4*)(outp + jj*4) = o;              // 4 consecutive 16B blocks/thread
    }
}

// ---------------------------------------------------------------------------
// DPP full-wave rotate-by-1: lane n <- lane (n-1)&63 (wave_ror:1 = 0x13C).
__device__ __forceinline__ float dpp_ror1_f32(float v) {
    union { float f; int i; } u, r;
    u.f = v;
    r.i = __builtin_amdgcn_update_dpp(0, u.i, 0x13C, 0xF, 0xF, false);
    return r.f;
}

// ---------------------------------------------------------------------------
// dp: forward Viterbi (f32), 16-wave ghost-zone tiling, transposed nc loads.
// Wave w: lanes 32-63 own auth columns w*32..w*32+31; lanes 0-31 ghost-copy
// the left wave's columns. col = w*32+lane-32; wave_ror1 provides col-1.
// Ghost lane 0 takes junk; corruption moves 1 lane/step -> at the 16-step
// refresh cadence at most ghost lanes 0-15 are stale; auth reads only lane 31.
// Loads: ncT[b][t/4][col][4] -> one float4 covers 4 steps; 4 float4/phase,
// double-buffered in REGISTERS (bufA/bufB, static indices; 32 VGPRs total —
// fits even a 64-VGPR cap; launch_bounds(1024,4) raises cap to 128 so R9's
// scratch spill cannot recur). dirs flushed every 2nd phase (32-t windows).
#define DIRS(j,w) dirs[((j)<<6) | ((w) ^ ((j) & 31))]

__global__ __launch_bounds__(1024, 4) void vits_dp(
    const float* __restrict__ ncT,
    const int* __restrict__ spec_len, const int* __restrict__ text_len,
    float* __restrict__ dur, float* __restrict__ logw, int* __restrict__ jt)
{
    __shared__ unsigned int dirs[TT*(TS/32)];   // 128 KB (swizzled)
    __shared__ float qrow2[2][TT];              // 4 KB (double-buffered)
    __shared__ int Tr[TT + 1];                  // 2 KB

    const int tid  = threadIdx.x;
    const int lane = tid & 63;
    const int wid  = tid >> 6;
    const int b = blockIdx.x;
    const int SL = spec_len[b], TL = text_len[b];
    const int col = (wid << 5) + lane - 32;      // auth if lane>=32, ghost else
    const bool auth = (lane >= 32);
    const bool w0g  = (wid == 0) && (lane < 32); // pinned-NEG ghost lanes
    const int colL = (col < 0) ? 0 : col;

    float q = (col == 0) ? 0.0f : NEGCF;
    unsigned int bits = 0;

    const float* base = ncT + (size_t)b*(TS/4)*GSTR + (size_t)colL*4;

    float4 bufA[4], bufB[4];
    #pragma unroll
    for (int i = 0; i < 4; ++i) bufA[i] = *(const float4*)(base + (size_t)i*GSTR);

#define PHASE(BUF, OBUF, PAR) do {                                           \
        const int gn = (tb + 16) >> 2;                                       \
        _Pragma("unroll")                                                    \
        for (int i = 0; i < 4; ++i) {                                        \
            int gi = gn + i; if (gi > TS/4 - 1) gi = TS/4 - 1;               \
            OBUF[i] = *(const float4*)(base + (size_t)gi*GSTR);              \
        }                                                                    \
        _Pragma("unroll")                                                    \
        for (int g4 = 0; g4 < 4; ++g4) {                                     \
            _Pragma("unroll")                                                \
            for (int k = 0; k < 4; ++k) {                                    \
                float f = ((const float*)&BUF[g4])[k];                       \
                float qp = dpp_ror1_f32(q);                                  \
                bool d = (qp >= q);                                          \
                bits = (bits << 1) | (unsigned)d;                            \
                float qn = f + fmaxf(qp, q);                                 \
                q = w0g ? NEGCF : qn;                                        \
            }                                                                \
        }                                                                    \
        if (tb & 16) { if (auth) DIRS(col, tb >> 5) = bits; bits = 0; }      \
        if (auth) qrow2[PAR][col] = q;                                       \
        __syncthreads();                                                     \
        if (!auth && wid) q = qrow2[PAR][col];                               \
    } while (0)

    int tb = 0;
    const int nph = SL >> 4;                     // 16-step phases
    for (int ph = 0; ph < nph; ++ph, tb += 16) {
        if ((ph & 1) == 0) PHASE(bufA, bufB, 0);
        else               PHASE(bufB, bufA, 1);
    }
    // tail (SL & 15 steps) — direct loads; bits may carry 16 bits from an
    // unflushed half-window (SL%32 >= 16), final flush below handles both.
    for (int t = tb; t < SL; ++t) {
        float f = base[((size_t)(t >> 2))*GSTR + (t & 3)];
        float qp = dpp_ror1_f32(q);
        bool d = (qp >= q);
        bits = (bits << 1) | (unsigned)d;
        float qn = f + fmaxf(qp, q);
        q = w0g ? NEGCF : qn;
    }
    if (SL & 31) {
        int w = SL >> 5, r = SL & 31;
        if (auth) DIRS(col, w) = bits << (32 - r);
    }
    __syncthreads();

    for (int i = tid; i <= TT; i += 1024) Tr[i] = 0;
    __syncthreads();

    if (tid == 0) {
        Tr[TL] = SL;
        int j = TL - 1, tc = SL - 1;
        // Tr[j] = first frame aligned to text index j (transition time)
        while (j > 0 && tc >= 0) {
            int w = tc >> 5;
            int bcur = 31 - (tc & 31);
            unsigned int W = DIRS(j, w) & (0xFFFFFFFFu << bcur);
            if (W) {
                int bp = __ffs(W) - 1;          // lowest set bit >= bcur
                int tp = (w << 5) + 31 - bp;    // = largest t' <= tc with d=1
                Tr[j] = tp;
                --j;
                tc = tp - 1;
            } else {
                if (w == 0) break;
                tc = (w << 5) - 1;
            }
        }
    }
    __syncthreads();

    for (int u = tid; u < TT; u += 1024) {
        float dv = (u < TL) ? (float)(Tr[u+1] - Tr[u]) : 0.0f;
        dur[b*TT + u] = dv;
        logw[b*TT + u] = (u < TL) ? logf(dv + 1e-6f) : 0.0f;
    }
    // jt: range-fill [Tr[u], Tr[u+1]) -> u
    for (int u = 0; u < TL; ++u) {
        int t1 = Tr[u+1];
        for (int t = Tr[u] + tid; t < t1; t += 1024) jt[b*TS + t] = u;
    }
    for (int t = SL + tid; t < TS; t += 1024) jt[b*TS + t] = -1;
}

// ---------------------------------------------------------------------------
// path: path[b][t][u] = (u == jt[b][t]) ? 1 : 0   (float4-vectorized)
__global__ void vits_path(const int* __restrict__ jt, float4* __restrict__ path)
{
    int idx = blockIdx.x*blockDim.x + threadIdx.x;
    const int total = BB*TS*(TT/4);
    for (; idx < total; idx += gridDim.x*blockDim.x) {
        int u4 = idx & (TT/4 - 1);
        int bt = idx >> 7;
        int j = jt[bt];
        float4 v = make_float4(0.f,0.f,0.f,0.f);
        int r = j - (u4 << 2);
        if (r >= 0 && r < 4) ((float*)&v)[r] = 1.f;
        path[idx] = v;
    }
}

// ---------------------------------------------------------------------------
// m/logs expansion: out[b][c][t] = (jt>=0) ? src[b][c][jt] : 0
__global__ void vits_mlexp(const int* __restrict__ jt,
    const float* __restrict__ m_p, const float* __restrict__ logs_p,
    float4* __restrict__ mexp, float4* __restrict__ lexp)
{
    int idx = blockIdx.x*blockDim.x + threadIdx.x;
    const int total = BB*CC*(TS/4);
    for (; idx < total; idx += gridDim.x*blockDim.x) {
        int t4 = idx & (TS/4 - 1);
        int bc = idx >> 9;
        int b = bc / CC;
        int4 jv = *(const int4*)(jt + b*TS + (t4 << 2));
        const float* mrow = m_p    + (size_t)bc*TT;
        const float* lrow = logs_p + (size_t)bc*TT;
        float4 mv, lv;
        mv.x = (jv.x >= 0) ? mrow[jv.x] : 0.f;  lv.x = (jv.x >= 0) ? lrow[jv.x] : 0.f;
        mv.y = (jv.y >= 0) ? mrow[jv.y] : 0.f;  lv.y = (jv.y >= 0) ? lrow[jv.y] : 0.f;
        mv.z = (jv.z >= 0) ? mrow[jv.z] : 0.f;  lv.z = (jv.z >= 0) ? lrow[jv.z] : 0.f;
        mv.w = (jv.w >= 0) ? mrow[jv.w] : 0.f;  lv.w = (jv.w >= 0) ? lrow[jv.w] : 0.f;
        mexp[idx] = mv;
        lexp[idx] = lv;
    }
}

// ---------------------------------------------------------------------------
extern "C" void kernel_launch(void* const* d_in, const int* in_sizes, int n_in,
                              void* d_out, int out_size, void* d_ws, size_t ws_size,
                              hipStream_t stream) {
    const float* z_p      = (const float*)d_in[0];
    const float* m_p      = (const float*)d_in[1];
    const float* logs_p   = (const float*)d_in[2];
    const int*   spec_len = (const int*)d_in[3];
    const int*   text_len = (const int*)d_in[4];
    float* out = (float*)d_out;

    float* Bmat = (float*)d_ws;                  // [B][384][512] f32 = 12.6 MB
    float* avec = Bmat + (size_t)BB*KK*TT;       // [B][512]
    int*   jt   = (int*)(avec + BB*TT);          // [B][2048]

    float* path  = out + OFF_PATH;   // doubles as ncT staging ([B][TS/4][TT][4])
    float* dur   = out + OFF_DUR;
    float* logw  = out + OFF_LOGW;
    float* mexp  = out + OFF_MEXP;
    float* lexp  = out + OFF_LEXP;
    float* tmask = out + OFF_TMASK;
    float* smask = out + OFF_SMASK;

    vits_prep<<<BB, 512, 0, stream>>>(m_p, logs_p, spec_len, text_len,
                                      Bmat, avec, tmask, smask);
    vits_gemm<<<dim3(TT/64, TS/64, BB), 256, 0, stream>>>(z_p, Bmat, avec, path);
    vits_dp<<<BB, 1024, 0, stream>>>(path, spec_len, text_len, dur, logw, jt);
    vits_path<<<2048, 256, 0, stream>>>(jt, (float4*)path);
    vits_mlexp<<<2048, 256, 0, stream>>>(jt, m_p, logs_p, (float4*)mexp, (float4*)lexp);
}